// Round 1
// baseline (83.600 us; speedup 1.0000x reference)
//
#include <hip/hip_runtime.h>

// AdjacencyAttention: B=4096, N=64, D=256, fp32 in/out.
// One block (256 threads) per batch element.
// Phases: stage(W2,W3,VsT) -> lhs/rhs dots -> t=tanh(outer+bs) in LDS ->
//         s=Vs@t (4x4 reg tiles) -> block softmax over 4096 -> store.

#define FMA4(acc, s, v)                         \
    acc.x = fmaf(s, v.x, acc.x);                \
    acc.y = fmaf(s, v.y, acc.y);                \
    acc.z = fmaf(s, v.z, acc.z);                \
    acc.w = fmaf(s, v.w, acc.w);

__global__ __launch_bounds__(256, 4) void adjatt_kernel(
    const float* __restrict__ x,   // (B,64,256)
    const float* __restrict__ W1,  // (1,)
    const float* __restrict__ W2,  // (256,1)
    const float* __restrict__ W3,  // (256,)
    const float* __restrict__ bs,  // (1,64,64)
    const float* __restrict__ Vs,  // (64,64)
    float* __restrict__ out)       // (B,64,64)
{
    constexpr int N = 64, D = 256;
    __shared__ __align__(16) float t_lds[N * N];     // 16 KB, t[j][k] stride 64
    __shared__ __align__(16) float vsT[N * 68];      // 17.4 KB, VsT[j][i] stride 68
    __shared__ __align__(16) float lhs[N];
    __shared__ __align__(16) float rhs[N];
    __shared__ __align__(16) float w2l[D];
    __shared__ __align__(16) float w3l[D];
    __shared__ float redm[4];
    __shared__ float reds[4];

    const int tid = threadIdx.x;
    const int b = blockIdx.x;

    // ---- Phase 0: stage small operands into LDS ----
    w2l[tid] = W2[tid];
    w3l[tid] = W3[tid];
#pragma unroll
    for (int it = 0; it < 16; ++it) {
        int e = it * 256 + tid;      // e = i*64 + j
        int i = e >> 6, j = e & 63;
        vsT[j * 68 + i] = Vs[e];     // transposed store (one-time; minor conflicts ok)
    }
    const float W1v = W1[0];
    __syncthreads();

    // ---- Phase 1: lhs[n] = (x[n,:]·W2)*W1 ; rhs[n] = x[n,:]·W3 ----
    {
        const int r = tid >> 2;      // row 0..63, 4 threads per row
        const int co = tid & 3;      // chunk within row
        const float4* xv = (const float4*)(x + (size_t)b * (N * D) + r * D);
        float d2 = 0.f, d3 = 0.f;
#pragma unroll
        for (int kk = 0; kk < 16; ++kk) {
            int idx = co + kk * 4;   // float4 index in row; lane-quads are 64B-contiguous
            float4 xr = xv[idx];
            float4 w2 = *(const float4*)&w2l[idx * 4];
            float4 w3 = *(const float4*)&w3l[idx * 4];
            d2 = fmaf(xr.x, w2.x, fmaf(xr.y, w2.y, fmaf(xr.z, w2.z, fmaf(xr.w, w2.w, d2))));
            d3 = fmaf(xr.x, w3.x, fmaf(xr.y, w3.y, fmaf(xr.z, w3.z, fmaf(xr.w, w3.w, d3))));
        }
        d2 += __shfl_xor(d2, 1); d2 += __shfl_xor(d2, 2);
        d3 += __shfl_xor(d3, 1); d3 += __shfl_xor(d3, 2);
        if (co == 0) { lhs[r] = d2 * W1v; rhs[r] = d3; }
    }
    __syncthreads();

    // ---- Phase 2: t[j][k] = tanh(lhs[j]*rhs[k] + bs[j][k]) ----
#pragma unroll
    for (int it = 0; it < 16; ++it) {
        int e = it * 256 + tid;
        int j = e >> 6, k = e & 63;
        float z = fmaf(lhs[j], rhs[k], bs[e]);
        // tanh(z) = 1 - 2/(exp(2z)+1); saturates correctly at +/-inf
        float e2 = __expf(2.f * z);
        float th = 1.f - __fdividef(2.f, e2 + 1.f);
        t_lds[e] = th;
    }
    __syncthreads();

    // ---- Phase 3: s = Vs @ t ; thread (ti,tk) owns rows 4ti..4ti+3, cols 4tk..4tk+3 ----
    const int ti = tid >> 4, tk = tid & 15;
    float4 a0 = {0, 0, 0, 0}, a1 = a0, a2 = a0, a3 = a0;
#pragma unroll 8
    for (int j = 0; j < 64; ++j) {
        float4 vs = *(const float4*)&vsT[j * 68 + ti * 4];  // Vs[4ti..4ti+3][j]
        float4 tv = *(const float4*)&t_lds[j * 64 + tk * 4]; // t[j][4tk..4tk+3]
        FMA4(a0, vs.x, tv);
        FMA4(a1, vs.y, tv);
        FMA4(a2, vs.z, tv);
        FMA4(a3, vs.w, tv);
    }

    // ---- Phase 4: softmax over all 4096 s-values of this batch ----
    const int lane = tid & 63, wid = tid >> 6;
    float m = fmaxf(fmaxf(fmaxf(a0.x, a0.y), fmaxf(a0.z, a0.w)),
             fmaxf(fmaxf(fmaxf(a1.x, a1.y), fmaxf(a1.z, a1.w)),
             fmaxf(fmaxf(fmaxf(a2.x, a2.y), fmaxf(a2.z, a2.w)),
                   fmaxf(fmaxf(a3.x, a3.y), fmaxf(a3.z, a3.w)))));
#pragma unroll
    for (int off = 1; off < 64; off <<= 1) m = fmaxf(m, __shfl_xor(m, off));
    if (lane == 0) redm[wid] = m;
    __syncthreads();
    const float M = fmaxf(fmaxf(redm[0], redm[1]), fmaxf(redm[2], redm[3]));

    // exponentiate in place, accumulate local sum
    float s = 0.f;
#define EXP4(acc)                                   \
    acc.x = __expf(acc.x - M); s += acc.x;          \
    acc.y = __expf(acc.y - M); s += acc.y;          \
    acc.z = __expf(acc.z - M); s += acc.z;          \
    acc.w = __expf(acc.w - M); s += acc.w;
    EXP4(a0); EXP4(a1); EXP4(a2); EXP4(a3);
#undef EXP4
#pragma unroll
    for (int off = 1; off < 64; off <<= 1) s += __shfl_xor(s, off);
    if (lane == 0) reds[wid] = s;
    __syncthreads();
    const float S = reds[0] + reds[1] + reds[2] + reds[3];
    const float inv = __fdividef(1.f, S);

    float* ob = out + (size_t)b * (N * N) + (ti * 4) * 64 + tk * 4;
#define ST4(acc, row)                                                   \
    {                                                                   \
        float4 v = {acc.x * inv, acc.y * inv, acc.z * inv, acc.w * inv}; \
        *(float4*)&ob[(row) * 64] = v;                                  \
    }
    ST4(a0, 0); ST4(a1, 1); ST4(a2, 2); ST4(a3, 3);
#undef ST4
}

extern "C" void kernel_launch(void* const* d_in, const int* in_sizes, int n_in,
                              void* d_out, int out_size, void* d_ws, size_t ws_size,
                              hipStream_t stream) {
    const float* x  = (const float*)d_in[0];
    const float* W1 = (const float*)d_in[1];
    const float* W2 = (const float*)d_in[2];
    const float* W3 = (const float*)d_in[3];
    const float* bs = (const float*)d_in[4];
    const float* Vs = (const float*)d_in[5];
    float* out = (float*)d_out;

    const int B = in_sizes[0] / (64 * 256);
    adjatt_kernel<<<dim3(B), dim3(256), 0, stream>>>(x, W1, W2, W3, bs, Vs, out);
}

// Round 2
// 69.737 us; speedup vs baseline: 1.1988x; 1.1988x over previous
//
#include <hip/hip_runtime.h>

// AdjacencyAttention: B=4096, N=64, D=256, fp32 in/out.
// One block (256 threads, 4 waves) per batch element.
//   P1: lhs/rhs dots (16 thr/row, weights in regs, coalesced 256B segs)
//   P2: t = tanh(outer+bs), split into bf16 hi/lo, stored [n][j] XOR-swizzled
//   P3: s = Vs @ t via mfma_f32_16x16x32_bf16, 3-product hi/lo split
//   P4: block softmax over 4096 scores, coalesced-ish stores

typedef float f32x4 __attribute__((ext_vector_type(4)));
typedef __bf16 bf16x8 __attribute__((ext_vector_type(8)));

__global__ __launch_bounds__(256, 4) void adjatt_kernel(
    const float* __restrict__ x,   // (B,64,256)
    const float* __restrict__ W1,  // (1,)
    const float* __restrict__ W2,  // (256,1)
    const float* __restrict__ W3,  // (256,)
    const float* __restrict__ bs,  // (1,64,64)
    const float* __restrict__ Vs,  // (64,64)
    float* __restrict__ out)       // (B,64,64)
{
    __shared__ __align__(16) unsigned char tT[16384]; // [0,8K): hi bf16 [n][j] swz; [8K,16K): lo
    __shared__ __align__(16) float lhs[64];
    __shared__ __align__(16) float rhs[64];
    __shared__ float redm[4], reds[4];

    const int tid  = threadIdx.x;
    const int b    = blockIdx.x;
    const int lane = tid & 63;
    const int w    = tid >> 6;

    const float W1v = W1[0];

    // ---- A fragments (Vs rows 16w..16w+15) direct from global, hi/lo split ----
    // A-frag layout (16x16x32): lane l holds A[l&15][8*(l>>4) + e], e=0..7 (k-contig)
    bf16x8 Ah[2], Al[2];
    {
        const int row = 16 * w + (lane & 15);
        #pragma unroll
        for (int s = 0; s < 2; ++s) {
            const float* vp = Vs + row * 64 + 32 * s + 8 * (lane >> 4);
            f32x4 f0 = *(const f32x4*)vp;
            f32x4 f1 = *(const f32x4*)(vp + 4);
            #pragma unroll
            for (int e = 0; e < 4; ++e) {
                __bf16 h0 = (__bf16)f0[e];
                Ah[s][e] = h0;
                Al[s][e] = (__bf16)(f0[e] - (float)h0);
                __bf16 h1 = (__bf16)f1[e];
                Ah[s][e + 4] = h1;
                Al[s][e + 4] = (__bf16)(f1[e] - (float)h1);
            }
        }
    }

    // ---- Phase 1: lhs[r] = (x[r,:]·W2)*W1 ; rhs[r] = x[r,:]·W3 ----
    {
        const int co = tid & 15;   // 16 threads per row
        const int r0 = tid >> 4;   // 0..15
        f32x4 w2v[4], w3v[4];
        #pragma unroll
        for (int kk = 0; kk < 4; ++kk) {
            w2v[kk] = *(const f32x4*)(W2 + 4 * (co + 16 * kk));
            w3v[kk] = *(const f32x4*)(W3 + 4 * (co + 16 * kk));
        }
        const float* xb = x + (size_t)b * 16384;
        #pragma unroll
        for (int it = 0; it < 4; ++it) {
            const int r = r0 + 16 * it;
            const float* xr = xb + r * 256;
            float d2 = 0.f, d3 = 0.f;
            #pragma unroll
            for (int kk = 0; kk < 4; ++kk) {
                f32x4 xv = *(const f32x4*)(xr + 4 * (co + 16 * kk));
                d2 = fmaf(xv[0], w2v[kk][0], d2); d2 = fmaf(xv[1], w2v[kk][1], d2);
                d2 = fmaf(xv[2], w2v[kk][2], d2); d2 = fmaf(xv[3], w2v[kk][3], d2);
                d3 = fmaf(xv[0], w3v[kk][0], d3); d3 = fmaf(xv[1], w3v[kk][1], d3);
                d3 = fmaf(xv[2], w3v[kk][2], d3); d3 = fmaf(xv[3], w3v[kk][3], d3);
            }
            d2 += __shfl_xor(d2, 1); d2 += __shfl_xor(d2, 2);
            d2 += __shfl_xor(d2, 4); d2 += __shfl_xor(d2, 8);
            d3 += __shfl_xor(d3, 1); d3 += __shfl_xor(d3, 2);
            d3 += __shfl_xor(d3, 4); d3 += __shfl_xor(d3, 8);
            if (co == 0) { lhs[r] = d2 * W1v; rhs[r] = d3; }
        }
    }
    __syncthreads();

    // ---- Phase 2: t[j][n] = tanh(lhs[j]*rhs[n] + bs[j][n]) -> tT[n][j] bf16 hi/lo ----
    {
        const int n  = lane;        // column
        const int j0 = 16 * w;      // this wave covers j0..j0+15
        const float rv = rhs[n];
        f32x4 lh[4];
        #pragma unroll
        for (int c = 0; c < 4; ++c) lh[c] = *(const f32x4*)&lhs[j0 + 4 * c];
        bf16x8 hi[2], lo[2];
        #pragma unroll
        for (int jj = 0; jj < 16; ++jj) {
            float z  = fmaf(lh[jj >> 2][jj & 3], rv, bs[(j0 + jj) * 64 + n]);
            float e2 = __expf(2.f * z);
            float th = 1.f - __fdividef(2.f, e2 + 1.f);  // tanh, saturates correctly
            __bf16 h = (__bf16)th;
            hi[jj >> 3][jj & 7] = h;
            lo[jj >> 3][jj & 7] = (__bf16)(th - (float)h);
        }
        #pragma unroll
        for (int c = 0; c < 2; ++c) {
            const int off = (n * 128 + (j0 + 8 * c) * 2) ^ ((n & 7) << 4);
            *(bf16x8*)(tT + off)        = hi[c];
            *(bf16x8*)(tT + 8192 + off) = lo[c];
        }
    }
    __syncthreads();

    // ---- Phase 3: s(rows 16w..16w+15, all 64 cols) = Vs @ t via MFMA ----
    // B-frag: lane l holds t[32s + 8*(l>>4) + e][16nt + (l&15)]  (k-contig in tT[n][j])
    f32x4 acc[4];
    #pragma unroll
    for (int nt = 0; nt < 4; ++nt) acc[nt] = (f32x4){0.f, 0.f, 0.f, 0.f};
    #pragma unroll
    for (int nt = 0; nt < 4; ++nt) {
        const int n = 16 * nt + (lane & 15);
        #pragma unroll
        for (int s = 0; s < 2; ++s) {
            const int off = (n * 128 + 64 * s + 16 * (lane >> 4)) ^ ((n & 7) << 4);
            bf16x8 Bh = *(const bf16x8*)(tT + off);
            bf16x8 Bl = *(const bf16x8*)(tT + 8192 + off);
            acc[nt] = __builtin_amdgcn_mfma_f32_16x16x32_bf16(Ah[s], Bh, acc[nt], 0, 0, 0);
            acc[nt] = __builtin_amdgcn_mfma_f32_16x16x32_bf16(Al[s], Bh, acc[nt], 0, 0, 0);
            acc[nt] = __builtin_amdgcn_mfma_f32_16x16x32_bf16(Ah[s], Bl, acc[nt], 0, 0, 0);
        }
    }

    // ---- Phase 4: softmax over all 4096 scores of this batch ----
    float m = acc[0][0];
    #pragma unroll
    for (int nt = 0; nt < 4; ++nt)
        #pragma unroll
        for (int e = 0; e < 4; ++e) m = fmaxf(m, acc[nt][e]);
    #pragma unroll
    for (int off = 1; off < 64; off <<= 1) m = fmaxf(m, __shfl_xor(m, off));
    if (lane == 0) redm[w] = m;
    __syncthreads();
    const float M = fmaxf(fmaxf(redm[0], redm[1]), fmaxf(redm[2], redm[3]));

    float ssum = 0.f;
    #pragma unroll
    for (int nt = 0; nt < 4; ++nt)
        #pragma unroll
        for (int e = 0; e < 4; ++e) {
            acc[nt][e] = __expf(acc[nt][e] - M);
            ssum += acc[nt][e];
        }
    #pragma unroll
    for (int off = 1; off < 64; off <<= 1) ssum += __shfl_xor(ssum, off);
    if (lane == 0) reds[w] = ssum;
    __syncthreads();
    const float inv = __fdividef(1.f, reds[0] + reds[1] + reds[2] + reds[3]);

    // ---- Store: D layout row = 16w + 4*(l>>4) + e, col = 16nt + (l&15) ----
    float* ob = out + (size_t)b * 4096;
    const int rbase = 16 * w + 4 * (lane >> 4);
    const int cbase = lane & 15;
    #pragma unroll
    for (int nt = 0; nt < 4; ++nt) {
        const int col = 16 * nt + cbase;
        #pragma unroll
        for (int e = 0; e < 4; ++e) {
            ob[(rbase + e) * 64 + col] = acc[nt][e] * inv;
        }
    }
}

extern "C" void kernel_launch(void* const* d_in, const int* in_sizes, int n_in,
                              void* d_out, int out_size, void* d_ws, size_t ws_size,
                              hipStream_t stream) {
    const float* x  = (const float*)d_in[0];
    const float* W1 = (const float*)d_in[1];
    const float* W2 = (const float*)d_in[2];
    const float* W3 = (const float*)d_in[3];
    const float* bs = (const float*)d_in[4];
    const float* Vs = (const float*)d_in[5];
    float* out = (float*)d_out;

    const int B = in_sizes[0] / (64 * 256);
    adjatt_kernel<<<dim3(B), dim3(256), 0, stream>>>(x, W1, W2, W3, bs, Vs, out);
}